// Round 9
// baseline (93.273 us; speedup 1.0000x reference)
//
#include <hip/hip_runtime.h>
#include <hip/hip_fp16.h>

// StableTTLayer TT forward, B=131072. Round 9.
// R8 post-mortem: main ~27us, latency-bound on the per-batch chain
// (ord LDS read -> vbuf read -> MFMA -> write, + exposed PKB column loads).
// R9: (1) flat per-stage batch-descriptor list (c|start|len packed uint),
//     built during sort phase, atomic slot assignment -> load-balanced,
//     waves stride i+=4.
// (2) full 2-deep software pipeline: prefetch NEXT batch's desc, ord, A-frags
//     AND Bv during current MFMA. Safe: within a stage each sample's vbuf
//     slot is touched only by its owning batch, so early read is race-free.
// Batch partition identical to R8 -> absmax must be bit-identical 4.547e-13.
// Tables/scales validated R5-R8 (256 * 16^4 * 256 = 2^32, undone at end).

#define B_TOTAL 131072
#define NDIM 64
#define RANK 32
#define S_BLK 256
#define THREADS 256
#define VSTRIDE_H 40   // halves per sample slot (80 B: 16B-aligned, bank-spread)
#define MAXB 80        // max batches per stage: sum ceil(cnt/16) <= 64+16

typedef _Float16 half8 __attribute__((ext_vector_type(8)));
typedef _Float16 half4 __attribute__((ext_vector_type(4)));
typedef float    f32x4 __attribute__((ext_vector_type(4)));

// ---------------- K1: build tables (unchanged from R7/R8, validated) --------
__global__ __launch_bounds__(256) void build_tables(
    const float* __restrict__ core0, const float* __restrict__ mid,
    const float* __restrict__ lastc,
    half8* __restrict__ PKB, __half* __restrict__ T01, float* __restrict__ TL)
{
    const int id = blockIdx.x * 256 + threadIdx.x;
    if (id < 32768) {
        const int l  = id & 63;
        const int f  = (id >> 6) & 1;
        const int c  = (id >> 7) & 63;
        const int tt = id >> 13;
        const int q = l >> 4, li = l & 15;
        const int n = f * 16 + li;
        const int t = 1 + tt;
        half8 h;
        #pragma unroll
        for (int j = 0; j < 8; ++j) {
            const int k = q * 8 + j;
            h[j] = (_Float16)(16.0f * mid[((t * 32 + k) * 64 + c) * 32 + n]);
        }
        PKB[id] = h;
    } else if (id < 163840) {
        const int i2 = id - 32768;
        const int s = i2 & 31, c1 = (i2 >> 5) & 63, c0 = i2 >> 11;
        float acc = 0.f;
        #pragma unroll
        for (int r = 0; r < 32; ++r)
            acc = fmaf(core0[c0 * 32 + r], mid[(r * 64 + c1) * 32 + s], acc);
        T01[(c0 * 64 + c1) * 32 + s] = __float2half(acc * 256.0f);
    } else {
        const int i3 = id - 163840;
        const int c7 = i3 & 63, c6 = (i3 >> 6) & 63, r = i3 >> 12;
        const float* m5 = mid + 5 * 65536;
        float acc = 0.f;
        #pragma unroll
        for (int s = 0; s < 32; ++s)
            acc = fmaf(m5[(r * 64 + c6) * 32 + s], lastc[s * 64 + c7], acc);
        TL[(c6 * 64 + c7) * 32 + r] = acc * 256.0f;
    }
}

// ---------------- K2: main --------------------------------------------------
__global__ __launch_bounds__(256) void tt_main_p(
    const int* __restrict__ idx, const __half* __restrict__ T01,
    const half8* __restrict__ PKB, const float* __restrict__ TL,
    float* __restrict__ out)
{
    __shared__ __align__(16) __half vbuf[S_BLK * VSTRIDE_H];  // 20 KB
    __shared__ unsigned short ord[4][S_BLK];                  // 2 KB
    __shared__ unsigned char  cols[S_BLK][8];                 // 2 KB
    __shared__ unsigned int   bases[4][65];                   // 1040 B
    __shared__ unsigned int   hist[4][64];                    // 1 KB
    __shared__ unsigned int   desc[4][MAXB];                  // 1280 B
    __shared__ unsigned int   nb[4];

    const int tid  = threadIdx.x;          // == sample id within block
    const int lane = tid & 63;
    const int wv   = tid >> 6;             // 0..3
    const int li   = lane & 15;
    const int quad = lane >> 4;
    const int b0   = blockIdx.x * S_BLK;

    // Phase 0: indices -> cols (coalesced); zero hist/nb
    #pragma unroll
    for (int k = 0; k < S_BLK * 8; k += THREADS) {
        const int lin = k + tid;
        int v = idx[b0 * 8 + lin];
        v = min(max(v, 0), NDIM - 1);
        cols[lin >> 3][lin & 7] = (unsigned char)v;
    }
    hist[tid >> 6][tid & 63] = 0;
    if (tid < 4) nb[tid] = 0;
    __syncthreads();

    // Phase 1: fused 4-key counting sort + batch descriptor lists
    unsigned int key[4], rank[4];
    #pragma unroll
    for (int tt = 0; tt < 4; ++tt) {
        key[tt]  = cols[tid][2 + tt];
        rank[tt] = atomicAdd(&hist[tt][key[tt]], 1u);
    }
    __syncthreads();
    {   // wave wv scans hist[wv] (64 bins, one lane each)
        const unsigned int v = hist[wv][lane];
        unsigned int inc = v;
        #pragma unroll
        for (int d = 1; d < 64; d <<= 1) {
            const unsigned int n = __shfl_up(inc, d);
            if (lane >= d) inc += n;
        }
        bases[wv][lane] = inc - v;
        if (lane == 63) bases[wv][64] = inc;   // == S_BLK
    }
    __syncthreads();
    #pragma unroll
    for (int tt = 0; tt < 4; ++tt)
        ord[tt][bases[tt][key[tt]] + rank[tt]] = (unsigned short)tid;
    {   // batch descriptors: thread (tts, c) emits ceil(cnt/16) descs
        const int tts = tid >> 6, c = tid & 63;
        const int st = (int)bases[tts][c], en = (int)bases[tts][c + 1];
        for (int p = st; p < en; p += 16) {
            const unsigned int ln = (unsigned int)min(16, en - p);
            const unsigned int slot = atomicAdd(&nb[tts], 1u);
            desc[tts][slot] = (unsigned int)c | ((unsigned int)p << 6) | (ln << 15);
        }
    }
    __syncthreads();

    // Phase 2: init v from T01 (8-lane groups; x256 true value)
    {
        const int g = tid & 7, gid = tid >> 3;
        #pragma unroll
        for (int it = 0; it < S_BLK / 32; ++it) {
            const int s = it * 32 + gid;
            const int c0 = cols[s][0], c1 = cols[s][1];
            const uint2 q = *reinterpret_cast<const uint2*>(
                T01 + (c0 * 64 + c1) * 32 + 4 * g);
            unsigned int* vp = reinterpret_cast<unsigned int*>(vbuf) + s * (VSTRIDE_H / 2);
            vp[2 * g]     = q.x;
            vp[2 * g + 1] = q.y;
        }
    }
    __syncthreads();

    // Phase 3: 4 middle stages; flat batch list, 2-deep software pipeline
    for (int tt = 0; tt < 4; ++tt) {
        const int n = (int)nb[tt];
        int i = wv;
        int sm = 0;
        half8 A0 = {0,0,0,0,0,0,0,0}, A1 = {0,0,0,0,0,0,0,0};
        half8 Bv = {0,0,0,0,0,0,0,0};
        if (i < n) {   // prologue: loads for first batch
            const unsigned int d = desc[tt][i];
            const int c = d & 63, st = (d >> 6) & 511, ln = (d >> 15) & 31;
            sm = (int)ord[tt][min(st + li, st + ln - 1)];
            A0 = PKB[((tt * 64 + c) * 2 + 0) * 64 + lane];
            A1 = PKB[((tt * 64 + c) * 2 + 1) * 64 + lane];
            Bv = *reinterpret_cast<const half8*>(
                reinterpret_cast<const char*>(vbuf) + sm * 80 + quad * 16);
        }
        while (i < n) {
            const int inx = i + 4;
            int smn = 0;
            half8 A0n = {0,0,0,0,0,0,0,0}, A1n = {0,0,0,0,0,0,0,0};
            half8 Bvn = {0,0,0,0,0,0,0,0};
            if (inx < n) {   // prefetch next batch (race-free within stage)
                const unsigned int d = desc[tt][inx];
                const int c = d & 63, st = (d >> 6) & 511, ln = (d >> 15) & 31;
                smn = (int)ord[tt][min(st + li, st + ln - 1)];
                A0n = PKB[((tt * 64 + c) * 2 + 0) * 64 + lane];
                A1n = PKB[((tt * 64 + c) * 2 + 1) * 64 + lane];
                Bvn = *reinterpret_cast<const half8*>(
                    reinterpret_cast<const char*>(vbuf) + smn * 80 + quad * 16);
            }
            // compute current batch: D = (M^T as A) x (V as B)
            f32x4 d0 = {0.f, 0.f, 0.f, 0.f}, d1 = {0.f, 0.f, 0.f, 0.f};
            d0 = __builtin_amdgcn_mfma_f32_16x16x32_f16(A0, Bv, d0, 0, 0, 0);
            d1 = __builtin_amdgcn_mfma_f32_16x16x32_f16(A1, Bv, d1, 0, 0, 0);
            // D: lane (q,li) = new_v[sample li][s_out = f*16 + q*4 + r]
            half4 w0, w1;
            #pragma unroll
            for (int r = 0; r < 4; ++r) {
                w0[r] = (_Float16)d0[r];
                w1[r] = (_Float16)d1[r];
            }
            char* base = reinterpret_cast<char*>(vbuf) + sm * 80 + quad * 8;
            *reinterpret_cast<half4*>(base)      = w0;   // s_out quad*4..+3
            *reinterpret_cast<half4*>(base + 32) = w1;   // s_out 16+quad*4..+3
            i = inx; sm = smn; A0 = A0n; A1 = A1n; Bv = Bvn;
        }
        __syncthreads();
    }

    // Phase 4: final contraction vs TL (x256), 8-lane reduce, undo 2^32
    {
        const int g = tid & 7, gid = tid >> 3;
        #pragma unroll
        for (int it = 0; it < S_BLK / 32; ++it) {
            const int s = it * 32 + gid;
            const int c6 = cols[s][6], c7 = cols[s][7];
            const unsigned int* vp =
                reinterpret_cast<const unsigned int*>(vbuf) + s * (VSTRIDE_H / 2);
            const __half2 v01 = *reinterpret_cast<const __half2*>(&vp[2 * g]);
            const __half2 v23 = *reinterpret_cast<const __half2*>(&vp[2 * g + 1]);
            const float4 L = *reinterpret_cast<const float4*>(
                TL + (c6 * 64 + c7) * 32 + 4 * g);
            float o = 0.f;
            o = fmaf(__low2float(v01),  L.x, o);
            o = fmaf(__high2float(v01), L.y, o);
            o = fmaf(__low2float(v23),  L.z, o);
            o = fmaf(__high2float(v23), L.w, o);
            o += __shfl_xor(o, 1);
            o += __shfl_xor(o, 2);
            o += __shfl_xor(o, 4);
            if (g == 0) out[b0 + s] = o * 2.3283064365386963e-10f;   // 2^-32
        }
    }
}

// ---------------- host ------------------------------------------------------
// ws: PKB 524288 B | TL 524288 B | T01 262144 B  (1310720 B total)
#define PKB_OFF 0u
#define TL_OFF  524288u
#define T01_OFF 1048576u

extern "C" void kernel_launch(void* const* d_in, const int* in_sizes, int n_in,
                              void* d_out, int out_size, void* d_ws, size_t ws_size,
                              hipStream_t stream) {
    const int*   idx   = (const int*)d_in[0];    // (B, 8) int32
    const float* core0 = (const float*)d_in[1];  // (1, 64, 32)
    const float* mid   = (const float*)d_in[2];  // (6, 32, 64, 32)
    const float* lastc = (const float*)d_in[3];  // (32, 64, 1)
    float* out = (float*)d_out;

    half8*  PKB = (half8*)((char*)d_ws + PKB_OFF);
    float*  TL  = (float*)((char*)d_ws + TL_OFF);
    __half* T01 = (__half*)((char*)d_ws + T01_OFF);

    hipLaunchKernelGGL(build_tables, dim3(294912 / 256), dim3(256), 0, stream,
                       core0, mid, lastc, PKB, T01, TL);
    hipLaunchKernelGGL(tt_main_p, dim3(B_TOTAL / S_BLK), dim3(THREADS), 0, stream,
                       idx, T01, PKB, TL, out);
}

// Round 10
// 83.950 us; speedup vs baseline: 1.1111x; 1.1111x over previous
//
#include <hip/hip_runtime.h>
#include <hip/hip_fp16.h>

// StableTTLayer TT forward, B=131072. Round 10: permutation-linked ping-pong.
// R8/R9 post-mortem: the per-batch serial LDS chain (bases->ord->vbuf, ~360cy)
// is the main kernel's floor; prefetch depth can't hide a chain with
// load-result->load-address hops. R10 removes the indirection from the READ
// path: vbuf is kept in stage-t sorted order (reads are affine: slot p+li),
// and the permutation moves to the WRITE side via a link table
// nxt[tt][p] = slot of the same sample in stage t+1's order (stage 3 links
// to sample order). Ping-pong double buffer dst/src. All steady-state loads
// (Bv, nxt, A-fragments) have affine addresses and are prefetched 2 columns
// ahead -> the only dependent path is Bv->MFMA->cvt->write (~60 cyc).
// Math identical to R5-R9: absmax must be exactly 4.547474e-13.
// Scales baked: 256 * 16^4 * 256 = 2^32, undone exactly at the end.

#define B_TOTAL 131072
#define NDIM 64
#define S_BLK 256
#define THREADS 256
#define VSH 40            // halves per v slot (80 B: 16B-aligned, bank-spread)

typedef _Float16 half8 __attribute__((ext_vector_type(8)));
typedef _Float16 half4 __attribute__((ext_vector_type(4)));
typedef float    f32x4 __attribute__((ext_vector_type(4)));

// ---------------- K1: build tables (unchanged from R7-R9, validated) --------
__global__ __launch_bounds__(256) void build_tables(
    const float* __restrict__ core0, const float* __restrict__ mid,
    const float* __restrict__ lastc,
    half8* __restrict__ PKB, __half* __restrict__ T01, float* __restrict__ TL)
{
    const int id = blockIdx.x * 256 + threadIdx.x;
    if (id < 32768) {
        const int l  = id & 63;
        const int f  = (id >> 6) & 1;
        const int c  = (id >> 7) & 63;
        const int tt = id >> 13;
        const int q = l >> 4, li = l & 15;
        const int n = f * 16 + li;
        const int t = 1 + tt;
        half8 h;
        #pragma unroll
        for (int j = 0; j < 8; ++j) {
            const int k = q * 8 + j;
            h[j] = (_Float16)(16.0f * mid[((t * 32 + k) * 64 + c) * 32 + n]);
        }
        PKB[id] = h;
    } else if (id < 163840) {
        const int i2 = id - 32768;
        const int s = i2 & 31, c1 = (i2 >> 5) & 63, c0 = i2 >> 11;
        float acc = 0.f;
        #pragma unroll
        for (int r = 0; r < 32; ++r)
            acc = fmaf(core0[c0 * 32 + r], mid[(r * 64 + c1) * 32 + s], acc);
        T01[(c0 * 64 + c1) * 32 + s] = __float2half(acc * 256.0f);
    } else {
        const int i3 = id - 163840;
        const int c7 = i3 & 63, c6 = (i3 >> 6) & 63, r = i3 >> 12;
        const float* m5 = mid + 5 * 65536;
        float acc = 0.f;
        #pragma unroll
        for (int s = 0; s < 32; ++s)
            acc = fmaf(m5[(r * 64 + c6) * 32 + s], lastc[s * 64 + c7], acc);
        TL[(c6 * 64 + c7) * 32 + r] = acc * 256.0f;
    }
}

// ---------------- K2: main --------------------------------------------------
__global__ __launch_bounds__(256) void tt_main_s(
    const int* __restrict__ idx, const __half* __restrict__ T01,
    const half8* __restrict__ PKB, const float* __restrict__ TL,
    float* __restrict__ out)
{
    __shared__ __align__(16) __half vbuf2[2][S_BLK * VSH];   // 40 KB ping-pong
    __shared__ unsigned char  cols[S_BLK][8];                // 2 KB
    __shared__ unsigned int   bases[4][65];                  // 1040 B
    __shared__ unsigned int   hist[4][64];                   // 1 KB
    __shared__ unsigned short nxt[4][S_BLK];                 // 2 KB link table
    __shared__ unsigned short pos0[S_BLK];                   // 512 B

    const int tid  = threadIdx.x;          // == sample id within block
    const int lane = tid & 63;
    const int wv   = tid >> 6;             // 0..3
    const int li   = lane & 15;
    const int quad = lane >> 4;
    const int b0   = blockIdx.x * S_BLK;

    // Phase 0: indices -> cols (coalesced); zero hist
    #pragma unroll
    for (int k = 0; k < S_BLK * 8; k += THREADS) {
        const int lin = k + tid;
        int v = idx[b0 * 8 + lin];
        v = min(max(v, 0), NDIM - 1);
        cols[lin >> 3][lin & 7] = (unsigned char)v;
    }
    hist[tid >> 6][tid & 63] = 0;
    __syncthreads();

    // Phase 1: fused 4-key counting sort + permutation links
    unsigned int key[4], rank[4];
    #pragma unroll
    for (int tt = 0; tt < 4; ++tt) {
        key[tt]  = cols[tid][2 + tt];
        rank[tt] = atomicAdd(&hist[tt][key[tt]], 1u);
    }
    __syncthreads();
    {   // wave wv scans hist[wv] (64 bins, one lane each)
        const unsigned int v = hist[wv][lane];
        unsigned int inc = v;
        #pragma unroll
        for (int d = 1; d < 64; d <<= 1) {
            const unsigned int n = __shfl_up(inc, d);
            if (lane >= d) inc += n;
        }
        bases[wv][lane] = inc - v;
        if (lane == 63) bases[wv][64] = inc;   // == S_BLK
    }
    __syncthreads();
    {   // per-sample positions in each stage order -> links
        unsigned int p[4];
        #pragma unroll
        for (int tt = 0; tt < 4; ++tt) p[tt] = bases[tt][key[tt]] + rank[tt];
        pos0[tid] = (unsigned short)p[0];
        #pragma unroll
        for (int tt = 0; tt < 3; ++tt) nxt[tt][p[tt]] = (unsigned short)p[tt + 1];
        nxt[3][p[3]] = (unsigned short)tid;    // last stage scatters to sample order
    }
    __syncthreads();

    // Phase 2: init v from T01 into buf0 at stage-0 positions (x256 true value)
    {
        const int g = tid & 7, gid = tid >> 3;
        #pragma unroll
        for (int it = 0; it < S_BLK / 32; ++it) {
            const int s = it * 32 + gid;
            const int c0 = cols[s][0], c1 = cols[s][1];
            const uint2 q = *reinterpret_cast<const uint2*>(
                T01 + (c0 * 64 + c1) * 32 + 4 * g);
            const int ps = (int)pos0[s];
            unsigned int* vp = reinterpret_cast<unsigned int*>(&vbuf2[0][ps * VSH]);
            vp[2 * g]     = q.x;
            vp[2 * g + 1] = q.y;
        }
    }
    __syncthreads();

    // Phase 3: 4 middle stages; affine reads, scatter writes, 2-col prefetch
    for (int tt = 0; tt < 4; ++tt) {
        const __half* src = vbuf2[tt & 1];
        __half*       dst = vbuf2[(tt + 1) & 1];
        const int cbase = wv * 16;
        // per-lane copy of this wave's 17 base values; __shfl(bval, j) = readlane
        const int bval = (int)bases[tt][cbase + (lane < 17 ? lane : 16)];

        int   stp[2], enp[2], wpp[2];
        half8 Afp[2][2], Bvp[2];
        #pragma unroll
        for (int j = 0; j < 2; ++j) {   // prologue: columns 0,1
            const int st = __shfl(bval, j);
            const int en = __shfl(bval, j + 1);
            const int c  = cbase + j;
            stp[j] = st; enp[j] = en;
            Afp[j][0] = PKB[((tt * 64 + c) * 2 + 0) * 64 + lane];
            Afp[j][1] = PKB[((tt * 64 + c) * 2 + 1) * 64 + lane];
            int pp = min(st + li, max(en - 1, st)); pp = min(pp, S_BLK - 1);
            wpp[j] = (int)nxt[tt][pp];
            Bvp[j] = *reinterpret_cast<const half8*>(&src[pp * VSH + quad * 8]);
        }
        #pragma unroll
        for (int ci = 0; ci < 16; ++ci) {
            const int cur = ci & 1;
            const int st = stp[cur], en = enp[cur];
            if (st < en) {   // wave-uniform
                f32x4 d0 = {0.f, 0.f, 0.f, 0.f}, d1 = {0.f, 0.f, 0.f, 0.f};
                d0 = __builtin_amdgcn_mfma_f32_16x16x32_f16(Afp[cur][0], Bvp[cur], d0, 0, 0, 0);
                d1 = __builtin_amdgcn_mfma_f32_16x16x32_f16(Afp[cur][1], Bvp[cur], d1, 0, 0, 0);
                // D: lane (q,li) = new_v[sample at pos st+li][s_out = f*16+q*4+r]
                half4 w0, w1;
                #pragma unroll
                for (int r = 0; r < 4; ++r) {
                    w0[r] = (_Float16)d0[r];
                    w1[r] = (_Float16)d1[r];
                }
                __half* base = &dst[wpp[cur] * VSH + quad * 4];
                *reinterpret_cast<half4*>(base)      = w0;   // s_out quad*4..+3
                *reinterpret_cast<half4*>(base + 16) = w1;   // s_out 16+quad*4..+3
                // rare overflow batches (bucket > 16): full chain inline
                for (int p = st + 16; p < en; p += 16) {
                    const int pp2 = min(p + li, en - 1);
                    const half8 Bx = *reinterpret_cast<const half8*>(
                        &src[pp2 * VSH + quad * 8]);
                    const int wx = (int)nxt[tt][pp2];
                    f32x4 e0 = {0.f, 0.f, 0.f, 0.f}, e1 = {0.f, 0.f, 0.f, 0.f};
                    e0 = __builtin_amdgcn_mfma_f32_16x16x32_f16(Afp[cur][0], Bx, e0, 0, 0, 0);
                    e1 = __builtin_amdgcn_mfma_f32_16x16x32_f16(Afp[cur][1], Bx, e1, 0, 0, 0);
                    half4 x0, x1;
                    #pragma unroll
                    for (int r = 0; r < 4; ++r) {
                        x0[r] = (_Float16)e0[r];
                        x1[r] = (_Float16)e1[r];
                    }
                    __half* bb = &dst[wx * VSH + quad * 4];
                    *reinterpret_cast<half4*>(bb)      = x0;
                    *reinterpret_cast<half4*>(bb + 16) = x1;
                }
            }
            if (ci + 2 < 16) {   // prefetch column ci+2 into the slot just freed
                const int j  = ci + 2;
                const int st2 = __shfl(bval, j);
                const int en2 = __shfl(bval, j + 1);
                const int c2  = cbase + j;
                stp[cur] = st2; enp[cur] = en2;
                Afp[cur][0] = PKB[((tt * 64 + c2) * 2 + 0) * 64 + lane];
                Afp[cur][1] = PKB[((tt * 64 + c2) * 2 + 1) * 64 + lane];
                int pp = min(st2 + li, max(en2 - 1, st2)); pp = min(pp, S_BLK - 1);
                wpp[cur] = (int)nxt[tt][pp];
                Bvp[cur] = *reinterpret_cast<const half8*>(&src[pp * VSH + quad * 8]);
            }
        }
        __syncthreads();
    }

    // Phase 4: final contraction vs TL from buf0 (sample order), undo 2^32
    {
        const int g = tid & 7, gid = tid >> 3;
        #pragma unroll
        for (int it = 0; it < S_BLK / 32; ++it) {
            const int s = it * 32 + gid;
            const int c6 = cols[s][6], c7 = cols[s][7];
            const unsigned int* vp =
                reinterpret_cast<const unsigned int*>(&vbuf2[0][s * VSH]);
            const __half2 v01 = *reinterpret_cast<const __half2*>(&vp[2 * g]);
            const __half2 v23 = *reinterpret_cast<const __half2*>(&vp[2 * g + 1]);
            const float4 L = *reinterpret_cast<const float4*>(
                TL + (c6 * 64 + c7) * 32 + 4 * g);
            float o = 0.f;
            o = fmaf(__low2float(v01),  L.x, o);
            o = fmaf(__high2float(v01), L.y, o);
            o = fmaf(__low2float(v23),  L.z, o);
            o = fmaf(__high2float(v23), L.w, o);
            o += __shfl_xor(o, 1);
            o += __shfl_xor(o, 2);
            o += __shfl_xor(o, 4);
            if (g == 0) out[b0 + s] = o * 2.3283064365386963e-10f;   // 2^-32
        }
    }
}

// ---------------- host ------------------------------------------------------
// ws: PKB 524288 B | TL 524288 B | T01 262144 B  (1310720 B total)
#define PKB_OFF 0u
#define TL_OFF  524288u
#define T01_OFF 1048576u

extern "C" void kernel_launch(void* const* d_in, const int* in_sizes, int n_in,
                              void* d_out, int out_size, void* d_ws, size_t ws_size,
                              hipStream_t stream) {
    const int*   idx   = (const int*)d_in[0];    // (B, 8) int32
    const float* core0 = (const float*)d_in[1];  // (1, 64, 32)
    const float* mid   = (const float*)d_in[2];  // (6, 32, 64, 32)
    const float* lastc = (const float*)d_in[3];  // (32, 64, 1)
    float* out = (float*)d_out;

    half8*  PKB = (half8*)((char*)d_ws + PKB_OFF);
    float*  TL  = (float*)((char*)d_ws + TL_OFF);
    __half* T01 = (__half*)((char*)d_ws + T01_OFF);

    hipLaunchKernelGGL(build_tables, dim3(294912 / 256), dim3(256), 0, stream,
                       core0, mid, lastc, PKB, T01, TL);
    hipLaunchKernelGGL(tt_main_s, dim3(B_TOTAL / S_BLK), dim3(THREADS), 0, stream,
                       idx, T01, PKB, TL, out);
}

// Round 11
// 82.020 us; speedup vs baseline: 1.1372x; 1.0235x over previous
//
#include <hip/hip_runtime.h>
#include <hip/hip_fp16.h>

// StableTTLayer TT forward, B=131072. Round 11: big-block amortization.
// R8/R9/R10 all plateau at main~27us despite different phase-3 structures ->
// binding constraint is the FIXED per-block per-stage cost: all 64 columns
// pay PKB fragment loads + >=1 MFMA batch + DS ops, while S_BLK=256 gives
// only 4 samples/bucket. R11: S_BLK=1024 (1 block/CU, 16 waves) -> buckets
// ~16/16 full: ~3x fewer batches/sample, 4x less PKB register traffic,
// 4x fewer barriers/sample. Needs 94 KB LDS -> dynamic shared + MaxDynamic-
// SharedMemorySize opt-in (CDNA4 has 160 KB/CU); deterministic fallback to
// an identical S_BLK=512 instantiation (48 KB) if the opt-in fails.
// In-place fixed-slot vbuf (validated race-free R8), 80 B stride (2-way-free
// banks), transposed MFMA D=(M^T)xV (validated R8-R10).
// Math identical to R5-R10: absmax must be exactly 4.547474e-13.
// Scales baked: 256 * 16^4 * 256 = 2^32, undone exactly at the end.

#define B_TOTAL 131072
#define NDIM 64

typedef _Float16 half8 __attribute__((ext_vector_type(8)));
typedef _Float16 half4 __attribute__((ext_vector_type(4)));
typedef float    f32x4 __attribute__((ext_vector_type(4)));

// ---------------- K1: build tables (unchanged from R7-R10, validated) -------
__global__ __launch_bounds__(256) void build_tables(
    const float* __restrict__ core0, const float* __restrict__ mid,
    const float* __restrict__ lastc,
    half8* __restrict__ PKB, __half* __restrict__ T01, float* __restrict__ TL)
{
    const int id = blockIdx.x * 256 + threadIdx.x;
    if (id < 32768) {
        const int l  = id & 63;
        const int f  = (id >> 6) & 1;
        const int c  = (id >> 7) & 63;
        const int tt = id >> 13;
        const int q = l >> 4, li = l & 15;
        const int n = f * 16 + li;
        const int t = 1 + tt;
        half8 h;
        #pragma unroll
        for (int j = 0; j < 8; ++j) {
            const int k = q * 8 + j;
            h[j] = (_Float16)(16.0f * mid[((t * 32 + k) * 64 + c) * 32 + n]);
        }
        PKB[id] = h;
    } else if (id < 163840) {
        const int i2 = id - 32768;
        const int s = i2 & 31, c1 = (i2 >> 5) & 63, c0 = i2 >> 11;
        float acc = 0.f;
        #pragma unroll
        for (int r = 0; r < 32; ++r)
            acc = fmaf(core0[c0 * 32 + r], mid[(r * 64 + c1) * 32 + s], acc);
        T01[(c0 * 64 + c1) * 32 + s] = __float2half(acc * 256.0f);
    } else {
        const int i3 = id - 163840;
        const int c7 = i3 & 63, c6 = (i3 >> 6) & 63, r = i3 >> 12;
        const float* m5 = mid + 5 * 65536;
        float acc = 0.f;
        #pragma unroll
        for (int s = 0; s < 32; ++s)
            acc = fmaf(m5[(r * 64 + c6) * 32 + s], lastc[s * 64 + c7], acc);
        TL[(c6 * 64 + c7) * 32 + r] = acc * 256.0f;
    }
}

// ---------------- K2: main (templated on block size) ------------------------
// dynamic smem layout (bytes): vbuf SBLK*80 | ord 4*SBLK*2 | cols2 SBLK*4 |
//                              hist 256*4 | bases 4*65*4
template<int SBLK>
__global__ __launch_bounds__(SBLK) void tt_main_v(
    const int* __restrict__ idx, const __half* __restrict__ T01,
    const half8* __restrict__ PKB, const float* __restrict__ TL,
    float* __restrict__ out)
{
    constexpr int NW  = SBLK / 64;   // waves per block
    constexpr int CPW = 64 / NW;     // columns per wave per stage
    extern __shared__ __align__(16) char smem[];
    __half*         vbuf  = reinterpret_cast<__half*>(smem);
    unsigned short* ord   = reinterpret_cast<unsigned short*>(smem + SBLK * 80);
    unsigned int*   cols2 = reinterpret_cast<unsigned int*>(smem + SBLK * 88);
    unsigned int*   hist  = reinterpret_cast<unsigned int*>(smem + SBLK * 92);
    unsigned int*   bases = hist + 256;

    const int tid  = threadIdx.x;        // == sample id within block
    const int lane = tid & 63;
    const int wv   = tid >> 6;
    const int li   = lane & 15;
    const int quad = lane >> 4;
    const int b0   = blockIdx.x * SBLK;

    // Phase 0: two coalesced int4 loads/thread; keys straight to registers
    const int4* idx4 = reinterpret_cast<const int4*>(idx) + (size_t)(b0 + tid) * 2;
    const int4 ia = idx4[0], ib = idx4[1];
    const int c0 = min(max(ia.x, 0), 63), c1 = min(max(ia.y, 0), 63);
    int key[4];
    key[0] = min(max(ia.z, 0), 63);
    key[1] = min(max(ia.w, 0), 63);
    key[2] = min(max(ib.x, 0), 63);
    key[3] = min(max(ib.y, 0), 63);
    const int c6 = min(max(ib.z, 0), 63), c7 = min(max(ib.w, 0), 63);
    cols2[tid] = (unsigned)c0 | ((unsigned)c1 << 8) |
                 ((unsigned)c6 << 16) | ((unsigned)c7 << 24);
    if (tid < 256) hist[tid] = 0;
    __syncthreads();

    // Phase 1: fused 4-key counting sort
    unsigned int rank[4];
    #pragma unroll
    for (int tt = 0; tt < 4; ++tt)
        rank[tt] = atomicAdd(&hist[tt * 64 + key[tt]], 1u);
    __syncthreads();
    if (wv < 4) {   // wave wv scans histogram wv (one lane per bin)
        const unsigned int v = hist[wv * 64 + lane];
        unsigned int inc = v;
        #pragma unroll
        for (int d = 1; d < 64; d <<= 1) {
            const unsigned int n = __shfl_up(inc, d);
            if (lane >= d) inc += n;
        }
        bases[wv * 65 + lane] = inc - v;
        if (lane == 63) bases[wv * 65 + 64] = inc;   // == SBLK
    }
    __syncthreads();
    #pragma unroll
    for (int tt = 0; tt < 4; ++tt)
        ord[tt * SBLK + bases[tt * 65 + key[tt]] + rank[tt]] = (unsigned short)tid;

    // Phase 2: init v from T01 (8-lane groups; x256 true value)
    __syncthreads();
    {
        const int g = tid & 7, gid = tid >> 3;
        #pragma unroll
        for (int it = 0; it < 8; ++it) {
            const int s = it * (SBLK / 8) + gid;
            const unsigned cc = cols2[s];
            const int a = cc & 255, b = (cc >> 8) & 255;
            const uint2 q = *reinterpret_cast<const uint2*>(
                T01 + (a * 64 + b) * 32 + 4 * g);
            unsigned int* vp = reinterpret_cast<unsigned int*>(vbuf + s * 40);
            vp[2 * g]     = q.x;
            vp[2 * g + 1] = q.y;
        }
    }
    __syncthreads();

    // Phase 3: 4 middle stages; in-place fixed slots, A-fragment prefetch
    for (int tt = 0; tt < 4; ++tt) {
        const int cbase = wv * CPW;
        half8 A0 = PKB[((tt * 64 + cbase) * 2 + 0) * 64 + lane];
        half8 A1 = PKB[((tt * 64 + cbase) * 2 + 1) * 64 + lane];
        for (int ci = 0; ci < CPW; ++ci) {
            const int c = cbase + ci;
            half8 nA0 = A0, nA1 = A1;
            if (ci + 1 < CPW) {
                nA0 = PKB[((tt * 64 + c + 1) * 2 + 0) * 64 + lane];
                nA1 = PKB[((tt * 64 + c + 1) * 2 + 1) * 64 + lane];
            }
            const int st = (int)bases[tt * 65 + c];
            const int en = (int)bases[tt * 65 + c + 1];
            for (int p = st; p < en; p += 16) {
                const int sm = (int)ord[tt * SBLK + min(p + li, en - 1)];
                const half8 Bv = *reinterpret_cast<const half8*>(
                    vbuf + sm * 40 + quad * 8);
                f32x4 d0 = {0.f, 0.f, 0.f, 0.f}, d1 = {0.f, 0.f, 0.f, 0.f};
                d0 = __builtin_amdgcn_mfma_f32_16x16x32_f16(A0, Bv, d0, 0, 0, 0);
                d1 = __builtin_amdgcn_mfma_f32_16x16x32_f16(A1, Bv, d1, 0, 0, 0);
                // D: lane (q,li) = new_v[sample sm(li)][s_out = f*16 + q*4 + r]
                half4 w0, w1;
                #pragma unroll
                for (int r = 0; r < 4; ++r) {
                    w0[r] = (_Float16)d0[r];
                    w1[r] = (_Float16)d1[r];
                }
                __half* basep = vbuf + sm * 40 + quad * 4;
                *reinterpret_cast<half4*>(basep)      = w0;   // s_out quad*4..+3
                *reinterpret_cast<half4*>(basep + 16) = w1;   // s_out 16+quad*4..+3
            }
            A0 = nA0; A1 = nA1;
        }
        __syncthreads();
    }

    // Phase 4: final contraction vs TL (x256), 8-lane reduce, undo 2^32
    {
        const int g = tid & 7, gid = tid >> 3;
        #pragma unroll
        for (int it = 0; it < 8; ++it) {
            const int s = it * (SBLK / 8) + gid;
            const unsigned cc = cols2[s];
            const int a = (cc >> 16) & 255, b = cc >> 24;
            const unsigned int* vp =
                reinterpret_cast<const unsigned int*>(vbuf + s * 40);
            const __half2 v01 = *reinterpret_cast<const __half2*>(&vp[2 * g]);
            const __half2 v23 = *reinterpret_cast<const __half2*>(&vp[2 * g + 1]);
            const float4 L = *reinterpret_cast<const float4*>(
                TL + (a * 64 + b) * 32 + 4 * g);
            float o = 0.f;
            o = fmaf(__low2float(v01),  L.x, o);
            o = fmaf(__high2float(v01), L.y, o);
            o = fmaf(__low2float(v23),  L.z, o);
            o = fmaf(__high2float(v23), L.w, o);
            o += __shfl_xor(o, 1);
            o += __shfl_xor(o, 2);
            o += __shfl_xor(o, 4);
            if (g == 0) out[b0 + s] = o * 2.3283064365386963e-10f;   // 2^-32
        }
    }
}

// ---------------- host ------------------------------------------------------
// ws: PKB 524288 B | TL 524288 B | T01 262144 B  (1310720 B total)
#define PKB_OFF 0u
#define TL_OFF  524288u
#define T01_OFF 1048576u
#define SMEM_BYTES(SBLK) ((SBLK) * 92 + 256 * 4 + 4 * 65 * 4)

extern "C" void kernel_launch(void* const* d_in, const int* in_sizes, int n_in,
                              void* d_out, int out_size, void* d_ws, size_t ws_size,
                              hipStream_t stream) {
    const int*   idx   = (const int*)d_in[0];    // (B, 8) int32
    const float* core0 = (const float*)d_in[1];  // (1, 64, 32)
    const float* mid   = (const float*)d_in[2];  // (6, 32, 64, 32)
    const float* lastc = (const float*)d_in[3];  // (32, 64, 1)
    float* out = (float*)d_out;

    half8*  PKB = (half8*)((char*)d_ws + PKB_OFF);
    float*  TL  = (float*)((char*)d_ws + TL_OFF);
    __half* T01 = (__half*)((char*)d_ws + T01_OFF);

    hipLaunchKernelGGL(build_tables, dim3(294912 / 256), dim3(256), 0, stream,
                       core0, mid, lastc, PKB, T01, TL);

    // Prefer 1024-thread blocks (94 KB LDS, needs opt-in); deterministic
    // fallback to 512-thread blocks (48 KB) if the opt-in is unsupported.
    // hipFuncSetAttribute is not a stream op -> graph-capture-safe; its
    // result is identical on every call (no state-dependent behavior).
    const hipError_t aerr = hipFuncSetAttribute(
        reinterpret_cast<const void*>(&tt_main_v<1024>),
        hipFuncAttributeMaxDynamicSharedMemorySize, SMEM_BYTES(1024));
    if (aerr == hipSuccess) {
        hipLaunchKernelGGL((tt_main_v<1024>), dim3(B_TOTAL / 1024), dim3(1024),
                           SMEM_BYTES(1024), stream, idx, T01, PKB, TL, out);
    } else {
        hipLaunchKernelGGL((tt_main_v<512>), dim3(B_TOTAL / 512), dim3(512),
                           SMEM_BYTES(512), stream, idx, T01, PKB, TL, out);
    }
}

// Round 12
// 79.332 us; speedup vs baseline: 1.1757x; 1.0339x over previous
//
#include <hip/hip_runtime.h>
#include <hip/hip_fp16.h>

// StableTTLayer TT forward, B=131072. Round 12: SBLK=512 on all 256 CUs.
// R11 post-mortem: SBLK=1024 -> grid 128 = HALF the CUs idle (and 1 block/CU
// at 94 KB LDS), which repaid the 3x batch amortization. R12 sets SBLK=512,
// grid=256 = exactly 1 block per CU (48 KB dynamic LDS, no opt-in):
//  - per-sample phases (idx load, sort, T01 init, TL final) spread over 2x CUs
//  - phase-3 per-SIMD batches ~79 (vs R11's 93 on the busy half)
//  - vs R10 (SBLK=256): half the fixed 64-column cost per sample.
// All math/tables identical to R5-R11: absmax must be exactly 4.547474e-13.
// Scales baked: 256 * 16^4 * 256 = 2^32, undone exactly at the end.

#define B_TOTAL 131072
#define NDIM 64
#define SBLK 512

typedef _Float16 half8 __attribute__((ext_vector_type(8)));
typedef _Float16 half4 __attribute__((ext_vector_type(4)));
typedef float    f32x4 __attribute__((ext_vector_type(4)));

// ---------------- K1: build tables (unchanged from R7-R11, validated) -------
__global__ __launch_bounds__(256) void build_tables(
    const float* __restrict__ core0, const float* __restrict__ mid,
    const float* __restrict__ lastc,
    half8* __restrict__ PKB, __half* __restrict__ T01, float* __restrict__ TL)
{
    const int id = blockIdx.x * 256 + threadIdx.x;
    if (id < 32768) {
        const int l  = id & 63;
        const int f  = (id >> 6) & 1;
        const int c  = (id >> 7) & 63;
        const int tt = id >> 13;
        const int q = l >> 4, li = l & 15;
        const int n = f * 16 + li;
        const int t = 1 + tt;
        half8 h;
        #pragma unroll
        for (int j = 0; j < 8; ++j) {
            const int k = q * 8 + j;
            h[j] = (_Float16)(16.0f * mid[((t * 32 + k) * 64 + c) * 32 + n]);
        }
        PKB[id] = h;
    } else if (id < 163840) {
        const int i2 = id - 32768;
        const int s = i2 & 31, c1 = (i2 >> 5) & 63, c0 = i2 >> 11;
        float acc = 0.f;
        #pragma unroll
        for (int r = 0; r < 32; ++r)
            acc = fmaf(core0[c0 * 32 + r], mid[(r * 64 + c1) * 32 + s], acc);
        T01[(c0 * 64 + c1) * 32 + s] = __float2half(acc * 256.0f);
    } else {
        const int i3 = id - 163840;
        const int c7 = i3 & 63, c6 = (i3 >> 6) & 63, r = i3 >> 12;
        const float* m5 = mid + 5 * 65536;
        float acc = 0.f;
        #pragma unroll
        for (int s = 0; s < 32; ++s)
            acc = fmaf(m5[(r * 64 + c6) * 32 + s], lastc[s * 64 + c7], acc);
        TL[(c6 * 64 + c7) * 32 + r] = acc * 256.0f;
    }
}

// ---------------- K2: main --------------------------------------------------
// dynamic smem layout (bytes): vbuf SBLK*80 | ord 4*SBLK*2 | cols2 SBLK*4 |
//                              hist 256*4 | bases 4*65*4   (~48 KB)
__global__ __launch_bounds__(SBLK) void tt_main_v(
    const int* __restrict__ idx, const __half* __restrict__ T01,
    const half8* __restrict__ PKB, const float* __restrict__ TL,
    float* __restrict__ out)
{
    constexpr int NW  = SBLK / 64;   // 8 waves
    constexpr int CPW = 64 / NW;     // 8 columns per wave per stage
    extern __shared__ __align__(16) char smem[];
    __half*         vbuf  = reinterpret_cast<__half*>(smem);
    unsigned short* ord   = reinterpret_cast<unsigned short*>(smem + SBLK * 80);
    unsigned int*   cols2 = reinterpret_cast<unsigned int*>(smem + SBLK * 88);
    unsigned int*   hist  = reinterpret_cast<unsigned int*>(smem + SBLK * 92);
    unsigned int*   bases = hist + 256;

    const int tid  = threadIdx.x;        // == sample id within block
    const int lane = tid & 63;
    const int wv   = tid >> 6;
    const int li   = lane & 15;
    const int quad = lane >> 4;
    const int b0   = blockIdx.x * SBLK;

    // Phase 0: two coalesced int4 loads/thread; keys straight to registers
    const int4* idx4 = reinterpret_cast<const int4*>(idx) + (size_t)(b0 + tid) * 2;
    const int4 ia = idx4[0], ib = idx4[1];
    const int c0 = min(max(ia.x, 0), 63), c1 = min(max(ia.y, 0), 63);
    int key[4];
    key[0] = min(max(ia.z, 0), 63);
    key[1] = min(max(ia.w, 0), 63);
    key[2] = min(max(ib.x, 0), 63);
    key[3] = min(max(ib.y, 0), 63);
    const int c6 = min(max(ib.z, 0), 63), c7 = min(max(ib.w, 0), 63);
    cols2[tid] = (unsigned)c0 | ((unsigned)c1 << 8) |
                 ((unsigned)c6 << 16) | ((unsigned)c7 << 24);
    if (tid < 256) hist[tid] = 0;
    __syncthreads();

    // Phase 1: fused 4-key counting sort
    unsigned int rank[4];
    #pragma unroll
    for (int tt = 0; tt < 4; ++tt)
        rank[tt] = atomicAdd(&hist[tt * 64 + key[tt]], 1u);
    __syncthreads();
    if (wv < 4) {   // wave wv scans histogram wv (one lane per bin)
        const unsigned int v = hist[wv * 64 + lane];
        unsigned int inc = v;
        #pragma unroll
        for (int d = 1; d < 64; d <<= 1) {
            const unsigned int n = __shfl_up(inc, d);
            if (lane >= d) inc += n;
        }
        bases[wv * 65 + lane] = inc - v;
        if (lane == 63) bases[wv * 65 + 64] = inc;   // == SBLK
    }
    __syncthreads();
    #pragma unroll
    for (int tt = 0; tt < 4; ++tt)
        ord[tt * SBLK + bases[tt * 65 + key[tt]] + rank[tt]] = (unsigned short)tid;

    // Phase 2: init v from T01 (8-lane groups; x256 true value)
    __syncthreads();
    {
        const int g = tid & 7, gid = tid >> 3;
        #pragma unroll
        for (int it = 0; it < 8; ++it) {
            const int s = it * (SBLK / 8) + gid;
            const unsigned cc = cols2[s];
            const int a = cc & 255, b = (cc >> 8) & 255;
            const uint2 q = *reinterpret_cast<const uint2*>(
                T01 + (a * 64 + b) * 32 + 4 * g);
            unsigned int* vp = reinterpret_cast<unsigned int*>(vbuf + s * 40);
            vp[2 * g]     = q.x;
            vp[2 * g + 1] = q.y;
        }
    }
    __syncthreads();

    // Phase 3: 4 middle stages; in-place fixed slots, A-fragment prefetch
    for (int tt = 0; tt < 4; ++tt) {
        const int cbase = wv * CPW;
        half8 A0 = PKB[((tt * 64 + cbase) * 2 + 0) * 64 + lane];
        half8 A1 = PKB[((tt * 64 + cbase) * 2 + 1) * 64 + lane];
        for (int ci = 0; ci < CPW; ++ci) {
            const int c = cbase + ci;
            half8 nA0 = A0, nA1 = A1;
            if (ci + 1 < CPW) {
                nA0 = PKB[((tt * 64 + c + 1) * 2 + 0) * 64 + lane];
                nA1 = PKB[((tt * 64 + c + 1) * 2 + 1) * 64 + lane];
            }
            const int st = (int)bases[tt * 65 + c];
            const int en = (int)bases[tt * 65 + c + 1];
            for (int p = st; p < en; p += 16) {
                const int sm = (int)ord[tt * SBLK + min(p + li, en - 1)];
                const half8 Bv = *reinterpret_cast<const half8*>(
                    vbuf + sm * 40 + quad * 8);
                f32x4 d0 = {0.f, 0.f, 0.f, 0.f}, d1 = {0.f, 0.f, 0.f, 0.f};
                d0 = __builtin_amdgcn_mfma_f32_16x16x32_f16(A0, Bv, d0, 0, 0, 0);
                d1 = __builtin_amdgcn_mfma_f32_16x16x32_f16(A1, Bv, d1, 0, 0, 0);
                // D: lane (q,li) = new_v[sample sm(li)][s_out = f*16 + q*4 + r]
                half4 w0, w1;
                #pragma unroll
                for (int r = 0; r < 4; ++r) {
                    w0[r] = (_Float16)d0[r];
                    w1[r] = (_Float16)d1[r];
                }
                __half* basep = vbuf + sm * 40 + quad * 4;
                *reinterpret_cast<half4*>(basep)      = w0;   // s_out quad*4..+3
                *reinterpret_cast<half4*>(basep + 16) = w1;   // s_out 16+quad*4..+3
            }
            A0 = nA0; A1 = nA1;
        }
        __syncthreads();
    }

    // Phase 4: final contraction vs TL (x256), 8-lane reduce, undo 2^32
    {
        const int g = tid & 7, gid = tid >> 3;
        #pragma unroll
        for (int it = 0; it < 8; ++it) {
            const int s = it * (SBLK / 8) + gid;
            const unsigned cc = cols2[s];
            const int a = (cc >> 16) & 255, b = cc >> 24;
            const unsigned int* vp =
                reinterpret_cast<const unsigned int*>(vbuf + s * 40);
            const __half2 v01 = *reinterpret_cast<const __half2*>(&vp[2 * g]);
            const __half2 v23 = *reinterpret_cast<const __half2*>(&vp[2 * g + 1]);
            const float4 L = *reinterpret_cast<const float4*>(
                TL + (a * 64 + b) * 32 + 4 * g);
            float o = 0.f;
            o = fmaf(__low2float(v01),  L.x, o);
            o = fmaf(__high2float(v01), L.y, o);
            o = fmaf(__low2float(v23),  L.z, o);
            o = fmaf(__high2float(v23), L.w, o);
            o += __shfl_xor(o, 1);
            o += __shfl_xor(o, 2);
            o += __shfl_xor(o, 4);
            if (g == 0) out[b0 + s] = o * 2.3283064365386963e-10f;   // 2^-32
        }
    }
}

// ---------------- host ------------------------------------------------------
// ws: PKB 524288 B | TL 524288 B | T01 262144 B  (1310720 B total)
#define PKB_OFF 0u
#define TL_OFF  524288u
#define T01_OFF 1048576u
#define SMEM_BYTES (SBLK * 92 + 256 * 4 + 4 * 65 * 4)   // ~48 KB, under default cap

extern "C" void kernel_launch(void* const* d_in, const int* in_sizes, int n_in,
                              void* d_out, int out_size, void* d_ws, size_t ws_size,
                              hipStream_t stream) {
    const int*   idx   = (const int*)d_in[0];    // (B, 8) int32
    const float* core0 = (const float*)d_in[1];  // (1, 64, 32)
    const float* mid   = (const float*)d_in[2];  // (6, 32, 64, 32)
    const float* lastc = (const float*)d_in[3];  // (32, 64, 1)
    float* out = (float*)d_out;

    half8*  PKB = (half8*)((char*)d_ws + PKB_OFF);
    float*  TL  = (float*)((char*)d_ws + TL_OFF);
    __half* T01 = (__half*)((char*)d_ws + T01_OFF);

    hipLaunchKernelGGL(build_tables, dim3(294912 / 256), dim3(256), 0, stream,
                       core0, mid, lastc, PKB, T01, TL);
    hipLaunchKernelGGL(tt_main_v, dim3(B_TOTAL / SBLK), dim3(SBLK),
                       SMEM_BYTES, stream, idx, T01, PKB, TL, out);
}

// Round 13
// 76.483 us; speedup vs baseline: 1.2195x; 1.0373x over previous
//
#include <hip/hip_runtime.h>
#include <hip/hip_fp16.h>

// StableTTLayer TT forward, B=131072. Round 13: 2x TLP at fixed amortization.
// R8-R12 post-mortem: every bucketed variant (22-27us) ran at 2 waves/SIMD;
// bottom-up op model says ~5-8us -> the gap is exposed latency at minimal
// occupancy, not structure. R13 keeps SBLK=512/grid=256 and ALL validated
// machinery (tables, fused sort, in-place 80B-stride vbuf, transposed MFMA)
// but uses 1024 threads/block = 16 waves/CU = 4 waves/SIMD:
//  - phase 0/1: thread owns half a sample (1 int4, 2 keys in registers;
//    LDS-atomic serialization halves)
//  - phase 2/4: 4 iters instead of 8;  phase 3: 16 waves x 4 columns.
// Math identical to R5-R12: absmax must be exactly 4.547474e-13.
// Scales baked: 256 * 16^4 * 256 = 2^32, undone exactly at the end.

#define B_TOTAL 131072
#define NDIM 64
#define SBLK 512
#define THREADS 1024

typedef _Float16 half8 __attribute__((ext_vector_type(8)));
typedef _Float16 half4 __attribute__((ext_vector_type(4)));
typedef float    f32x4 __attribute__((ext_vector_type(4)));

// ---------------- K1: build tables (unchanged from R7-R12, validated) -------
__global__ __launch_bounds__(256) void build_tables(
    const float* __restrict__ core0, const float* __restrict__ mid,
    const float* __restrict__ lastc,
    half8* __restrict__ PKB, __half* __restrict__ T01, float* __restrict__ TL)
{
    const int id = blockIdx.x * 256 + threadIdx.x;
    if (id < 32768) {
        const int l  = id & 63;
        const int f  = (id >> 6) & 1;
        const int c  = (id >> 7) & 63;
        const int tt = id >> 13;
        const int q = l >> 4, li = l & 15;
        const int n = f * 16 + li;
        const int t = 1 + tt;
        half8 h;
        #pragma unroll
        for (int j = 0; j < 8; ++j) {
            const int k = q * 8 + j;
            h[j] = (_Float16)(16.0f * mid[((t * 32 + k) * 64 + c) * 32 + n]);
        }
        PKB[id] = h;
    } else if (id < 163840) {
        const int i2 = id - 32768;
        const int s = i2 & 31, c1 = (i2 >> 5) & 63, c0 = i2 >> 11;
        float acc = 0.f;
        #pragma unroll
        for (int r = 0; r < 32; ++r)
            acc = fmaf(core0[c0 * 32 + r], mid[(r * 64 + c1) * 32 + s], acc);
        T01[(c0 * 64 + c1) * 32 + s] = __float2half(acc * 256.0f);
    } else {
        const int i3 = id - 163840;
        const int c7 = i3 & 63, c6 = (i3 >> 6) & 63, r = i3 >> 12;
        const float* m5 = mid + 5 * 65536;
        float acc = 0.f;
        #pragma unroll
        for (int s = 0; s < 32; ++s)
            acc = fmaf(m5[(r * 64 + c6) * 32 + s], lastc[s * 64 + c7], acc);
        TL[(c6 * 64 + c7) * 32 + r] = acc * 256.0f;
    }
}

// ---------------- K2: main --------------------------------------------------
// dynamic smem (bytes): vbuf SBLK*80 | ord 4*SBLK*2 | colkey 2*SBLK*4 |
//                       hist 256*4 | bases 4*65*4   (~50 KB)
__global__ __launch_bounds__(THREADS) void tt_main_w(
    const int* __restrict__ idx, const __half* __restrict__ T01,
    const half8* __restrict__ PKB, const float* __restrict__ TL,
    float* __restrict__ out)
{
    constexpr int NW  = THREADS / 64;  // 16 waves
    constexpr int CPW = 64 / NW;       // 4 columns per wave per stage
    extern __shared__ __align__(16) char smem[];
    __half*         vbuf   = reinterpret_cast<__half*>(smem);
    unsigned short* ord    = reinterpret_cast<unsigned short*>(smem + SBLK * 80);
    unsigned int*   colkey = reinterpret_cast<unsigned int*>(smem + SBLK * 88);
    unsigned int*   hist   = reinterpret_cast<unsigned int*>(smem + SBLK * 96);
    unsigned int*   bases  = hist + 256;

    const int tid  = threadIdx.x;
    const int lane = tid & 63;
    const int wv   = tid >> 6;         // 0..15
    const int li   = lane & 15;
    const int quad = lane >> 4;
    const int b0   = blockIdx.x * SBLK;

    // Phase 0: one coalesced int4 per thread (sample sid, half h)
    const int sid = tid >> 1, h = tid & 1;
    const int4 iv = reinterpret_cast<const int4*>(idx)[(size_t)b0 * 2 + tid];
    const int e0 = min(max(iv.x, 0), 63), e1 = min(max(iv.y, 0), 63);
    const int e2 = min(max(iv.z, 0), 63), e3 = min(max(iv.w, 0), 63);
    // h==0: e = (c0,c1,key0,key1)  ->  colkey[tid] = c0|c1<<8|k0<<16|k1<<24
    // h==1: e = (key2,key3,c6,c7)  ->  colkey[tid] = k2|k3<<8|c6<<16|c7<<24
    colkey[tid] = (unsigned)e0 | ((unsigned)e1 << 8) |
                  ((unsigned)e2 << 16) | ((unsigned)e3 << 24);
    const int k0 = h ? e0 : e2;        // this thread's two sort keys
    const int k1 = h ? e1 : e3;
    const int ts0 = h * 2, ts1 = h * 2 + 1;
    if (tid < 256) hist[tid] = 0;
    __syncthreads();

    // Phase 1: fused 4-key counting sort (2 keys per thread, in registers)
    const unsigned int r0 = atomicAdd(&hist[ts0 * 64 + k0], 1u);
    const unsigned int r1 = atomicAdd(&hist[ts1 * 64 + k1], 1u);
    __syncthreads();
    if (wv < 4) {   // wave wv scans histogram wv (one lane per bin)
        const unsigned int v = hist[wv * 64 + lane];
        unsigned int inc = v;
        #pragma unroll
        for (int d = 1; d < 64; d <<= 1) {
            const unsigned int n = __shfl_up(inc, d);
            if (lane >= d) inc += n;
        }
        bases[wv * 65 + lane] = inc - v;
        if (lane == 63) bases[wv * 65 + 64] = inc;   // == SBLK
    }
    __syncthreads();
    ord[ts0 * SBLK + bases[ts0 * 65 + k0] + r0] = (unsigned short)sid;
    ord[ts1 * SBLK + bases[ts1 * 65 + k1] + r1] = (unsigned short)sid;

    // Phase 2: init v from T01 (8-lane groups; x256 true value); fixed slots
    {
        const int g = tid & 7, gid = tid >> 3;   // gid 0..127
        #pragma unroll
        for (int it = 0; it < 4; ++it) {
            const int s = it * 128 + gid;
            const unsigned cc = colkey[2 * s];   // c0 | c1<<8 | ...
            const int a = cc & 255, b = (cc >> 8) & 255;
            const uint2 q = *reinterpret_cast<const uint2*>(
                T01 + (a * 64 + b) * 32 + 4 * g);
            unsigned int* vp = reinterpret_cast<unsigned int*>(vbuf + s * 40);
            vp[2 * g]     = q.x;
            vp[2 * g + 1] = q.y;
        }
    }
    __syncthreads();

    // Phase 3: 4 middle stages; 16 waves x 4 columns; A-fragment prefetch
    for (int tt = 0; tt < 4; ++tt) {
        const int cbase = wv * CPW;
        half8 A0 = PKB[((tt * 64 + cbase) * 2 + 0) * 64 + lane];
        half8 A1 = PKB[((tt * 64 + cbase) * 2 + 1) * 64 + lane];
        for (int ci = 0; ci < CPW; ++ci) {
            const int c = cbase + ci;
            half8 nA0 = A0, nA1 = A1;
            if (ci + 1 < CPW) {
                nA0 = PKB[((tt * 64 + c + 1) * 2 + 0) * 64 + lane];
                nA1 = PKB[((tt * 64 + c + 1) * 2 + 1) * 64 + lane];
            }
            const int st = (int)bases[tt * 65 + c];
            const int en = (int)bases[tt * 65 + c + 1];
            for (int p = st; p < en; p += 16) {
                const int sm = (int)ord[tt * SBLK + min(p + li, en - 1)];
                const half8 Bv = *reinterpret_cast<const half8*>(
                    vbuf + sm * 40 + quad * 8);
                f32x4 d0 = {0.f, 0.f, 0.f, 0.f}, d1 = {0.f, 0.f, 0.f, 0.f};
                d0 = __builtin_amdgcn_mfma_f32_16x16x32_f16(A0, Bv, d0, 0, 0, 0);
                d1 = __builtin_amdgcn_mfma_f32_16x16x32_f16(A1, Bv, d1, 0, 0, 0);
                // D: lane (q,li) = new_v[sample sm(li)][s_out = f*16 + q*4 + r]
                half4 w0, w1;
                #pragma unroll
                for (int r = 0; r < 4; ++r) {
                    w0[r] = (_Float16)d0[r];
                    w1[r] = (_Float16)d1[r];
                }
                __half* basep = vbuf + sm * 40 + quad * 4;
                *reinterpret_cast<half4*>(basep)      = w0;   // s_out quad*4..+3
                *reinterpret_cast<half4*>(basep + 16) = w1;   // s_out 16+quad*4..+3
            }
            A0 = nA0; A1 = nA1;
        }
        __syncthreads();
    }

    // Phase 4: final contraction vs TL (x256), 8-lane reduce, undo 2^32
    {
        const int g = tid & 7, gid = tid >> 3;
        #pragma unroll
        for (int it = 0; it < 4; ++it) {
            const int s = it * 128 + gid;
            const unsigned cc = colkey[2 * s + 1];   // ... | c6<<16 | c7<<24
            const int a = (cc >> 16) & 255, b = cc >> 24;
            const unsigned int* vp =
                reinterpret_cast<const unsigned int*>(vbuf + s * 40);
            const __half2 v01 = *reinterpret_cast<const __half2*>(&vp[2 * g]);
            const __half2 v23 = *reinterpret_cast<const __half2*>(&vp[2 * g + 1]);
            const float4 L = *reinterpret_cast<const float4*>(
                TL + (a * 64 + b) * 32 + 4 * g);
            float o = 0.f;
            o = fmaf(__low2float(v01),  L.x, o);
            o = fmaf(__high2float(v01), L.y, o);
            o = fmaf(__low2float(v23),  L.z, o);
            o = fmaf(__high2float(v23), L.w, o);
            o += __shfl_xor(o, 1);
            o += __shfl_xor(o, 2);
            o += __shfl_xor(o, 4);
            if (g == 0) out[b0 + s] = o * 2.3283064365386963e-10f;   // 2^-32
        }
    }
}

// ---------------- host ------------------------------------------------------
// ws: PKB 524288 B | TL 524288 B | T01 262144 B  (1310720 B total)
#define PKB_OFF 0u
#define TL_OFF  524288u
#define T01_OFF 1048576u
#define SMEM_BYTES (SBLK * 96 + 256 * 4 + 4 * 65 * 4)   // ~50.3 KB

extern "C" void kernel_launch(void* const* d_in, const int* in_sizes, int n_in,
                              void* d_out, int out_size, void* d_ws, size_t ws_size,
                              hipStream_t stream) {
    const int*   idx   = (const int*)d_in[0];    // (B, 8) int32
    const float* core0 = (const float*)d_in[1];  // (1, 64, 32)
    const float* mid   = (const float*)d_in[2];  // (6, 32, 64, 32)
    const float* lastc = (const float*)d_in[3];  // (32, 64, 1)
    float* out = (float*)d_out;

    half8*  PKB = (half8*)((char*)d_ws + PKB_OFF);
    float*  TL  = (float*)((char*)d_ws + TL_OFF);
    __half* T01 = (__half*)((char*)d_ws + T01_OFF);

    hipLaunchKernelGGL(build_tables, dim3(294912 / 256), dim3(256), 0, stream,
                       core0, mid, lastc, PKB, T01, TL);
    hipLaunchKernelGGL(tt_main_w, dim3(B_TOTAL / SBLK), dim3(THREADS),
                       SMEM_BYTES, stream, idx, T01, PKB, TL, out);
}